// Round 4
// baseline (271.559 us; speedup 1.0000x reference)
//
#include <hip/hip_runtime.h>

// Dims fixed by the problem: B=64, C=8, N=512, E=512, H=8, dh=64
// logits out: [B, C*N] = 262144 floats at d_out[0]
// Q3 out:     [B, C, E] = 262144 floats at d_out[262144]

typedef _Float16 f16x8 __attribute__((ext_vector_type(8)));
typedef float f32x4 __attribute__((ext_vector_type(4)));

__device__ __forceinline__ void async16(const void* g, void* l) {
  __builtin_amdgcn_global_load_lds(
      (const __attribute__((address_space(1))) unsigned int*)g,
      (__attribute__((address_space(3))) unsigned int*)l, 16, 0, 0);
}

// ---------------- prep: colsum(Wk2) + convert Wk1/Wv to f16 ----------------
__global__ __launch_bounds__(256) void prep_w(const float* __restrict__ Wk1,
                                              const float* __restrict__ Wv,
                                              const float* __restrict__ Wk2,
                                              _Float16* __restrict__ W1h,
                                              _Float16* __restrict__ W2h,
                                              float* __restrict__ colsum) {
  const int bid = blockIdx.x;
  if (bid < 16) {
    const int tx = threadIdx.x & 31, ty = threadIdx.x >> 5;
    const int col = bid * 32 + tx;
    float s = 0.f;
#pragma unroll 4
    for (int e = ty * 64; e < ty * 64 + 64; ++e) s += Wk2[e * 512 + col];
    __shared__ float red[8][32];
    red[ty][tx] = s;
    __syncthreads();
    if (ty == 0) {
      float t = 0.f;
#pragma unroll
      for (int g = 0; g < 8; ++g) t += red[g][tx];
      colsum[col] = t;
    }
  } else {
    const int cb = bid - 16;
    const float* src = (cb < 128) ? Wk1 : Wv;
    _Float16* dst = (cb < 128) ? W1h : W2h;
    const size_t off = (size_t)(cb & 127) * 2048 + threadIdx.x * 8;
    float4 a = *(const float4*)(src + off);
    float4 b = *(const float4*)(src + off + 4);
    union { _Float16 h[8]; uint4 u; } pk;
    pk.h[0] = (_Float16)a.x; pk.h[1] = (_Float16)a.y;
    pk.h[2] = (_Float16)a.z; pk.h[3] = (_Float16)a.w;
    pk.h[4] = (_Float16)b.x; pk.h[5] = (_Float16)b.y;
    pk.h[6] = (_Float16)b.z; pk.h[7] = (_Float16)b.w;
    *(uint4*)(dst + off) = pk.u;
  }
}

// ---------------- Q1 = [ge | sc] @ [Wqf | Wqs].T  (K=1026) -----------------
__global__ __launch_bounds__(256) void q1_mfma_kernel(
    const float* __restrict__ ge, const float* __restrict__ sc,
    const float* __restrict__ Wqf, const float* __restrict__ Wqs,
    float* __restrict__ Q1) {
  const int mb = blockIdx.x, nb = blockIdx.y, ks = blockIdx.z;
  const int tid = threadIdx.x;
  const int lane = tid & 63, wave = tid >> 6;
  const int wm = (wave >> 1) * 32, wn = (wave & 1) * 32;

  __shared__ __align__(16) _Float16 As[64][40];
  __shared__ __align__(16) _Float16 Ws[64][40];

  f32x4 acc[2][2] = {};
  const int qd = (lane >> 4) * 8, rr = lane & 15;

  for (int kt = 0; kt < 9; ++kt) {
    const int kb = ks * 288 + kt * 32;
#pragma unroll
    for (int f0 = 0; f0 < 2; ++f0) {
      int f = tid + f0 * 256;
      int r = f >> 3, c4 = (f & 7) * 4;
      int m = mb * 64 + r;
      int e = nb * 64 + r;
#pragma unroll
      for (int j = 0; j < 4; ++j) {
        int k = kb + c4 + j;
        float a = 0.f, w = 0.f;
        if (k < 512) {
          a = ge[(m >> 3) * 512 + k];
          w = Wqf[(size_t)e * 512 + k];
        } else if (k < 1026) {
          a = sc[(size_t)m * 514 + (k - 512)];
          w = Wqs[(size_t)e * 514 + (k - 512)];
        }
        As[r][c4 + j] = (_Float16)a;
        Ws[r][c4 + j] = (_Float16)w;
      }
    }
    __syncthreads();
    f16x8 af[2], bfr[2];
#pragma unroll
    for (int mi = 0; mi < 2; ++mi) af[mi] = *(const f16x8*)&As[wm + mi * 16 + rr][qd];
#pragma unroll
    for (int ni = 0; ni < 2; ++ni) bfr[ni] = *(const f16x8*)&Ws[wn + ni * 16 + rr][qd];
#pragma unroll
    for (int mi = 0; mi < 2; ++mi)
#pragma unroll
      for (int ni = 0; ni < 2; ++ni)
        acc[mi][ni] =
            __builtin_amdgcn_mfma_f32_16x16x32_f16(af[mi], bfr[ni], acc[mi][ni], 0, 0, 0);
    __syncthreads();
  }

  const int col = lane & 15, rq = (lane >> 4) * 4;
#pragma unroll
  for (int mi = 0; mi < 2; ++mi)
#pragma unroll
    for (int ni = 0; ni < 2; ++ni)
#pragma unroll
      for (int r = 0; r < 4; ++r) {
        int m = mb * 64 + wm + mi * 16 + rq + r;
        int e = nb * 64 + wn + ni * 16 + col;
        atomicAdd(&Q1[(size_t)m * 512 + e], acc[mi][ni][r]);
      }
}

// ---------------- fused K1+V GEMM + k2sum; writes K1 and V-transposed ------
// Grid 1024 flat, XCD-swizzled: xcd = bid&7; the 4 nb-blocks sharing an
// A-tile land on the same XCD, temporally adjacent -> A fetched once.
__global__ __launch_bounds__(256, 2) void gemm_kv(
    const float* __restrict__ A, const _Float16* __restrict__ W1,
    const _Float16* __restrict__ W2, const float* __restrict__ colsum,
    _Float16* __restrict__ K1, _Float16* __restrict__ Vt,
    float* __restrict__ k2sum) {
  const int bid = blockIdx.x;
  const int xcd = bid & 7, ii = bid >> 3;
  const int nb = ii & 3, mb = xcd * 32 + (ii >> 2);
  const int tid = threadIdx.x, lane = tid & 63, wave = tid >> 6;
  const int wm = (wave >> 1) * 64, wn = (wave & 1) * 64;
  const int row0 = mb * 128, col0 = nb * 128;
  const int b = mb >> 2;  // 128-row tiles never cross batch boundaries

  __shared__ __align__(16) _Float16 As[128][72];    // padded, uniform b128 reads
  __shared__ __align__(16) _Float16 Wbuf[2][128 * 64];  // W1s/W2s; reused as Vts

  f32x4 acc1[4][4] = {}, acc2[4][4] = {};
  float k2p[4] = {};
  const int qd = (lane >> 4) * 8, rr = lane & 15;
  const int wlr = lane >> 3, wlc = lane & 7;

  for (int kt = 0; kt < 8; ++kt) {
    const int kbase = kt * 64;
#pragma unroll
    for (int j = 0; j < 4; ++j) {
      int r = wave * 32 + j * 8 + wlr;
      int c = wlc ^ (r & 7);
      size_t goff = (size_t)(col0 + r) * 512 + kbase + c * 8;
      async16(W1 + goff, &Wbuf[0][(wave * 32 + j * 8) * 64]);
      async16(W2 + goff, &Wbuf[1][(wave * 32 + j * 8) * 64]);
    }
#pragma unroll
    for (int i = 0; i < 4; ++i) {
      int f = tid + i * 256;
      int r = f >> 3, c8 = (f & 7) * 8;
      const float* ap = A + (size_t)(row0 + r) * 512 + kbase + c8;
      float4 a0 = *(const float4*)ap;
      float4 a1 = *(const float4*)(ap + 4);
      union { _Float16 h[8]; uint4 u; } pk;
      pk.h[0] = (_Float16)a0.x; pk.h[1] = (_Float16)a0.y;
      pk.h[2] = (_Float16)a0.z; pk.h[3] = (_Float16)a0.w;
      pk.h[4] = (_Float16)a1.x; pk.h[5] = (_Float16)a1.y;
      pk.h[6] = (_Float16)a1.z; pk.h[7] = (_Float16)a1.w;
      *(uint4*)&As[r][c8] = pk.u;
      if (nb == 0) {  // fused k2sum partial: each (row,k) staged exactly once
        const float* cp = colsum + kbase + c8;
        float4 c0 = *(const float4*)cp;
        float4 c1 = *(const float4*)(cp + 4);
        k2p[i] += a0.x * c0.x + a0.y * c0.y + a0.z * c0.z + a0.w * c0.w +
                  a1.x * c1.x + a1.y * c1.y + a1.z * c1.z + a1.w * c1.w;
      }
    }
    __syncthreads();
#pragma unroll
    for (int k0 = 0; k0 < 64; k0 += 32) {
      const int q = (k0 >> 3) + (lane >> 4);
      f16x8 af[4], b1[4], b2[4];
#pragma unroll
      for (int mi = 0; mi < 4; ++mi)
        af[mi] = *(const f16x8*)&As[wm + mi * 16 + rr][k0 + qd];
#pragma unroll
      for (int ni = 0; ni < 4; ++ni) {
        int rw = wn + ni * 16 + rr;
        int slot = q ^ (rw & 7);
        b1[ni] = *(const f16x8*)&Wbuf[0][rw * 64 + slot * 8];
        b2[ni] = *(const f16x8*)&Wbuf[1][rw * 64 + slot * 8];
      }
#pragma unroll
      for (int mi = 0; mi < 4; ++mi)
#pragma unroll
        for (int ni = 0; ni < 4; ++ni) {
          acc1[mi][ni] =
              __builtin_amdgcn_mfma_f32_16x16x32_f16(af[mi], b1[ni], acc1[mi][ni], 0, 0, 0);
          acc2[mi][ni] =
              __builtin_amdgcn_mfma_f32_16x16x32_f16(af[mi], b2[ni], acc2[mi][ni], 0, 0, 0);
        }
    }
    __syncthreads();
  }

  if (nb == 0) {
#pragma unroll
    for (int i = 0; i < 4; ++i) {
      int r = (tid + i * 256) >> 3;
      atomicAdd(&k2sum[row0 + r], k2p[i]);
    }
  }

  const int col = lane & 15, rq = (lane >> 4) * 4;
  // K1: natural [n][e] layout, scalar f16 stores (16-lane x 2B contiguous = 32B)
#pragma unroll
  for (int mi = 0; mi < 4; ++mi)
#pragma unroll
    for (int ni = 0; ni < 4; ++ni)
#pragma unroll
      for (int r = 0; r < 4; ++r) {
        size_t m = row0 + wm + mi * 16 + rq + r;
        size_t e = col0 + wn + ni * 16 + col;
        K1[m * 512 + e] = (_Float16)acc1[mi][ni][r];
      }

  // V transposed: register frags -> swizzled LDS tile -> coalesced 256B stores
  _Float16* Vts = &Wbuf[0][0];  // 128 e-rows x 128 n, 16B-chunk-XOR swizzled
#pragma unroll
  for (int mi = 0; mi < 4; ++mi)
#pragma unroll
    for (int ni = 0; ni < 4; ++ni) {
      int n0 = wm + mi * 16 + rq;       // 4 consecutive n
      int el = wn + ni * 16 + col;      // e-row
      int cn = n0 >> 3, half = (n0 >> 2) & 1;
      int slot = cn ^ (el & 7);
      union { _Float16 h[4]; unsigned long long u; } pk;
#pragma unroll
      for (int r = 0; r < 4; ++r) pk.h[r] = (_Float16)acc2[mi][ni][r];
      *(unsigned long long*)&Vts[el * 128 + slot * 8 + half * 4] = pk.u;
    }
  __syncthreads();
  const int nbase = row0 & 511;
#pragma unroll
  for (int i = 0; i < 8; ++i) {
    int f = tid + i * 256;          // 2048 chunks: 128 e-rows x 16 chunks
    int el = f >> 4, c16 = f & 15;
    int slot = c16 ^ (el & 7);
    uint4 val = *(const uint4*)&Vts[el * 128 + slot * 8];
    *(uint4*)(Vt + (size_t)b * 262144 + (size_t)(col0 + el) * 512 + nbase + c16 * 8) = val;
  }
}

// ---------------- attention: one block per (b,h), all-MFMA -----------------
__global__ __launch_bounds__(256) void attn_kernel(
    const float* __restrict__ Q1, const _Float16* __restrict__ K1,
    const _Float16* __restrict__ Vt, const int* __restrict__ mask,
    float* __restrict__ heads) {
  const int bid = blockIdx.x;  // 512
  const int b = bid >> 3, h = bid & 7;
  const int tid = threadIdx.x, wave = tid >> 6, lane = tid & 63;
  const int q = lane >> 4, cl = lane & 15;

  __shared__ __align__(16) _Float16 kt[256 * 64];  // 32KB: K-half or Vt-half
  __shared__ __align__(16) _Float16 P[16][520];    // unnormalized probs, f16
  __shared__ float red[4][8];

  // Q A-fragment: A[m=c][k=d], rows 8-15 duplicate rows 0-7 (outputs ignored)
  f16x8 af[2];
  {
    const float* qp = Q1 + (size_t)(b * 8 + (cl & 7)) * 512 + h * 64 + q * 8;
#pragma unroll
    for (int s = 0; s < 2; ++s) {
      float4 l0 = *(const float4*)(qp + s * 32);
      float4 l1 = *(const float4*)(qp + s * 32 + 4);
      af[s][0] = (_Float16)l0.x; af[s][1] = (_Float16)l0.y;
      af[s][2] = (_Float16)l0.z; af[s][3] = (_Float16)l0.w;
      af[s][4] = (_Float16)l1.x; af[s][5] = (_Float16)l1.y;
      af[s][6] = (_Float16)l1.z; af[s][7] = (_Float16)l1.w;
    }
  }

  // ---- QK^T: scores[c][n] for n in 2 halves of 256 ----
  f32x4 acc[8] = {};
  const _Float16* Kb = K1 + (size_t)b * 262144 + h * 64;
  for (int h2 = 0; h2 < 2; ++h2) {
#pragma unroll
    for (int j = 0; j < 8; ++j) {
      int r = wave * 64 + j * 8 + (lane >> 3);
      int cg = (lane & 7) ^ (r & 7);
      async16(Kb + (size_t)(h2 * 256 + r) * 512 + cg * 8, &kt[(wave * 64 + j * 8) * 64]);
    }
    __syncthreads();
#pragma unroll
    for (int tt = 0; tt < 4; ++tt) {
      int rn = wave * 64 + tt * 16 + cl;
#pragma unroll
      for (int s = 0; s < 2; ++s) {
        int slot = (s * 4 + q) ^ (cl & 7);
        f16x8 bf = *(const f16x8*)&kt[rn * 64 + slot * 8];
        acc[h2 * 4 + tt] =
            __builtin_amdgcn_mfma_f32_16x16x32_f16(af[s], bf, acc[h2 * 4 + tt], 0, 0, 0);
      }
    }
    __syncthreads();
  }

  // ---- softmax over n (rows c = q*4+r, valid q<2); P unnormalized ----
  float gmax[4], rsum[4];
  if (q < 2) {
    float mx[4] = {-3e38f, -3e38f, -3e38f, -3e38f};
#pragma unroll
    for (int t = 0; t < 8; ++t) {
      int n = (t >> 2) * 256 + wave * 64 + (t & 3) * 16 + cl;
#pragma unroll
      for (int r = 0; r < 4; ++r) {
        int c = q * 4 + r;
        float x = mask[(size_t)(b * 8 + c) * 512 + n] ? -1e9f : acc[t][r] * 0.125f;
        acc[t][r] = x;
        mx[r] = fmaxf(mx[r], x);
      }
    }
#pragma unroll
    for (int off = 1; off < 16; off <<= 1)
#pragma unroll
      for (int r = 0; r < 4; ++r) mx[r] = fmaxf(mx[r], __shfl_xor(mx[r], off, 64));
    if (cl == 0)
#pragma unroll
      for (int r = 0; r < 4; ++r) red[wave][q * 4 + r] = mx[r];
  }
  __syncthreads();
  if (q < 2) {
#pragma unroll
    for (int r = 0; r < 4; ++r) {
      int c = q * 4 + r;
      gmax[r] = fmaxf(fmaxf(red[0][c], red[1][c]), fmaxf(red[2][c], red[3][c]));
    }
  }
  __syncthreads();
  if (q < 2) {
#pragma unroll
    for (int r = 0; r < 4; ++r) rsum[r] = 0.f;
#pragma unroll
    for (int t = 0; t < 8; ++t) {
      int n = (t >> 2) * 256 + wave * 64 + (t & 3) * 16 + cl;
#pragma unroll
      for (int r = 0; r < 4; ++r) {
        float e = __expf(acc[t][r] - gmax[r]);
        rsum[r] += e;
        P[q * 4 + r][n] = (_Float16)e;
      }
    }
#pragma unroll
    for (int off = 1; off < 16; off <<= 1)
#pragma unroll
      for (int r = 0; r < 4; ++r) rsum[r] += __shfl_xor(rsum[r], off, 64);
    if (cl == 0)
#pragma unroll
      for (int r = 0; r < 4; ++r) red[wave][q * 4 + r] = rsum[r];
  }
  __syncthreads();

  // ---- PV: heads[c][e-slice] = P @ V; wave owns e-tile wave ----
  f32x4 pacc = {};
  const _Float16* Vb = Vt + (size_t)b * 262144 + (size_t)h * 64 * 512;
  for (int h2 = 0; h2 < 2; ++h2) {
#pragma unroll
    for (int j = 0; j < 8; ++j) {
      int r = wave * 16 + j * 2 + (lane >> 5);
      int cg = (lane & 31) ^ (r & 7);
      async16(Vb + (size_t)r * 512 + h2 * 256 + cg * 8, &kt[(wave * 16 + j * 2) * 256]);
    }
    __syncthreads();
    int rn = wave * 16 + cl;
#pragma unroll
    for (int sl = 0; sl < 8; ++sl) {
      int slot = (sl * 4 + q) ^ (cl & 7);
      f16x8 bf = *(const f16x8*)&kt[rn * 256 + slot * 8];
      f16x8 pa = *(const f16x8*)&P[cl][h2 * 256 + sl * 32 + q * 8];
      pacc = __builtin_amdgcn_mfma_f32_16x16x32_f16(pa, bf, pacc, 0, 0, 0);
    }
    __syncthreads();
  }

  if (q < 2) {
#pragma unroll
    for (int r = 0; r < 4; ++r) {
      int c = q * 4 + r;
      float inv = 1.f / (red[0][c] + red[1][c] + red[2][c] + red[3][c]);
      heads[(size_t)(b * 8 + c) * 512 + h * 64 + wave * 16 + cl] = pacc[r] * inv;
    }
  }
}

// ---------------- Q3 = heads @ Wout.T, 64x64 tiles, K-split 2 --------------
__global__ __launch_bounds__(256) void gemm_out64(const float* __restrict__ A,
                                                  const float* __restrict__ W,
                                                  float* __restrict__ C) {
  const int mb = blockIdx.x, nb = blockIdx.y, ks = blockIdx.z;
  const int tid = threadIdx.x;
  const int lane = tid & 63, wave = tid >> 6;
  const int wm = (wave >> 1) * 32, wn = (wave & 1) * 32;

  __shared__ __align__(16) _Float16 As[64][40];
  __shared__ __align__(16) _Float16 Ws[64][40];

  f32x4 acc[2][2] = {};
  const int qd = (lane >> 4) * 8, rr = lane & 15;

  for (int kt = 0; kt < 8; ++kt) {
    const int kb = ks * 256 + kt * 32;
#pragma unroll
    for (int f0 = 0; f0 < 2; ++f0) {
      int f = tid + f0 * 256;
      int r = f >> 3, c4 = (f & 7) * 4;
      float4 a = *(const float4*)(A + (size_t)(mb * 64 + r) * 512 + kb + c4);
      float4 w = *(const float4*)(W + (size_t)(nb * 64 + r) * 512 + kb + c4);
      As[r][c4 + 0] = (_Float16)a.x; As[r][c4 + 1] = (_Float16)a.y;
      As[r][c4 + 2] = (_Float16)a.z; As[r][c4 + 3] = (_Float16)a.w;
      Ws[r][c4 + 0] = (_Float16)w.x; Ws[r][c4 + 1] = (_Float16)w.y;
      Ws[r][c4 + 2] = (_Float16)w.z; Ws[r][c4 + 3] = (_Float16)w.w;
    }
    __syncthreads();
    f16x8 af[2], bfr[2];
#pragma unroll
    for (int mi = 0; mi < 2; ++mi) af[mi] = *(const f16x8*)&As[wm + mi * 16 + rr][qd];
#pragma unroll
    for (int ni = 0; ni < 2; ++ni) bfr[ni] = *(const f16x8*)&Ws[wn + ni * 16 + rr][qd];
#pragma unroll
    for (int mi = 0; mi < 2; ++mi)
#pragma unroll
      for (int ni = 0; ni < 2; ++ni)
        acc[mi][ni] =
            __builtin_amdgcn_mfma_f32_16x16x32_f16(af[mi], bfr[ni], acc[mi][ni], 0, 0, 0);
    __syncthreads();
  }

  const int col = lane & 15, rq = (lane >> 4) * 4;
#pragma unroll
  for (int mi = 0; mi < 2; ++mi)
#pragma unroll
    for (int ni = 0; ni < 2; ++ni)
#pragma unroll
      for (int r = 0; r < 4; ++r) {
        int m = mb * 64 + wm + mi * 16 + rq + r;
        int e = nb * 64 + wn + ni * 16 + col;
        atomicAdd(&C[(size_t)m * 512 + e], acc[mi][ni][r]);
      }
}

// ---------------- fused u_scalar + logits ----------------------------------
__global__ __launch_bounds__(256) void logits_u_kernel(
    const float* __restrict__ Q1, const float* __restrict__ v,
    const float* __restrict__ k2s, const int* __restrict__ mask,
    float* __restrict__ out) {
  const int bc = blockIdx.x;
  const int b = bc >> 3;
  const int tid = threadIdx.x;
  const int wave = tid >> 6, lane = tid & 63;

  float p = tanhf(Q1[(size_t)bc * 512 + tid]) * v[tid] +
            tanhf(Q1[(size_t)bc * 512 + tid + 256]) * v[tid + 256];
#pragma unroll
  for (int off = 32; off; off >>= 1) p += __shfl_down(p, off, 64);
  __shared__ float red[4];
  __shared__ float su;
  if (lane == 0) red[wave] = p;
  __syncthreads();
  if (tid == 0) su = red[0] + red[1] + red[2] + red[3];
  __syncthreads();
  const float u = su;

#pragma unroll
  for (int i = 0; i < 2; ++i) {
    int n = tid + i * 256;
    int idx = bc * 512 + n;
    out[idx] = mask[idx] ? -1e9f
                         : 10.f * tanhf(u * k2s[b * 512 + n] * 0.04419417382415922f);
  }
}

extern "C" void kernel_launch(void* const* d_in, const int* in_sizes, int n_in,
                              void* d_out, int out_size, void* d_ws, size_t ws_size,
                              hipStream_t stream) {
  const float* ne = (const float*)d_in[0];
  const float* ge = (const float*)d_in[1];
  const float* sc = (const float*)d_in[2];
  const int* mask = (const int*)d_in[3];
  const float* Wk1 = (const float*)d_in[4];
  const float* Wv = (const float*)d_in[5];
  const float* Wk2 = (const float*)d_in[6];
  const float* Wqf = (const float*)d_in[7];
  const float* Wout = (const float*)d_in[8];
  const float* Wqs = (const float*)d_in[9];
  const float* v = (const float*)d_in[10];

  float* logits = (float*)d_out;
  float* q3 = (float*)d_out + 262144;

  char* ws = (char*)d_ws;
  _Float16* K1 = (_Float16*)(ws + 0);          // 33,554,432 B  [b][n][e]
  _Float16* Vt = (_Float16*)(ws + 33554432);   // 33,554,432 B  [b][e][n]
  float* Q1 = (float*)(ws + 67108864);         // 1,048,576 B
  float* heads = (float*)(ws + 68157440);      // 1,048,576 B
  float* k2sum = (float*)(ws + 69206016);      // 131,072 B
  float* colsum = (float*)(ws + 69337088);     // 2,048 B
  _Float16* W1h = (_Float16*)(ws + 69339136);  // 524,288 B
  _Float16* W2h = (_Float16*)(ws + 69863424);  // 524,288 B

  hipMemsetAsync(Q1, 0, 1048576, stream);
  hipMemsetAsync(q3, 0, 1048576, stream);
  hipMemsetAsync(k2sum, 0, 131072, stream);
  prep_w<<<272, 256, 0, stream>>>(Wk1, Wv, Wk2, W1h, W2h, colsum);
  q1_mfma_kernel<<<dim3(8, 8, 4), 256, 0, stream>>>(ge, sc, Wqf, Wqs, Q1);
  gemm_kv<<<1024, 256, 0, stream>>>(ne, W1h, W2h, colsum, K1, Vt, k2sum);
  attn_kernel<<<512, 256, 0, stream>>>(Q1, K1, Vt, mask, heads);
  gemm_out64<<<dim3(8, 8, 2), 256, 0, stream>>>(heads, Wout, q3);
  logits_u_kernel<<<512, 256, 0, stream>>>(Q1, v, k2sum, mask, logits);
}

// Round 7
// 225.528 us; speedup vs baseline: 1.2041x; 1.2041x over previous
//
#include <hip/hip_runtime.h>

// Dims fixed by the problem: B=64, C=8, N=512, E=512, H=8, dh=64
// logits out: [B, C*N] = 262144 floats at d_out[0]
// Q3 out:     [B, C, E] = 262144 floats at d_out[262144]

typedef _Float16 f16x8 __attribute__((ext_vector_type(8)));
typedef float f32x4 __attribute__((ext_vector_type(4)));

__device__ __forceinline__ void async16(const void* g, void* l) {
  __builtin_amdgcn_global_load_lds(
      (const __attribute__((address_space(1))) unsigned int*)g,
      (__attribute__((address_space(3))) unsigned int*)l, 16, 0, 0);
}

// ---------------- prep: colsum(Wk2) + convert Wk1/Wv to f16 ----------------
__global__ __launch_bounds__(256) void prep_w(const float* __restrict__ Wk1,
                                              const float* __restrict__ Wv,
                                              const float* __restrict__ Wk2,
                                              _Float16* __restrict__ W1h,
                                              _Float16* __restrict__ W2h,
                                              float* __restrict__ colsum) {
  const int bid = blockIdx.x;
  if (bid < 16) {
    const int tx = threadIdx.x & 31, ty = threadIdx.x >> 5;
    const int col = bid * 32 + tx;
    float s = 0.f;
#pragma unroll 4
    for (int e = ty * 64; e < ty * 64 + 64; ++e) s += Wk2[e * 512 + col];
    __shared__ float red[8][32];
    red[ty][tx] = s;
    __syncthreads();
    if (ty == 0) {
      float t = 0.f;
#pragma unroll
      for (int g = 0; g < 8; ++g) t += red[g][tx];
      colsum[col] = t;
    }
  } else {
    const int cb = bid - 16;
    const float* src = (cb < 128) ? Wk1 : Wv;
    _Float16* dst = (cb < 128) ? W1h : W2h;
    const size_t off = (size_t)(cb & 127) * 2048 + threadIdx.x * 8;
    float4 a = *(const float4*)(src + off);
    float4 b = *(const float4*)(src + off + 4);
    union { _Float16 h[8]; uint4 u; } pk;
    pk.h[0] = (_Float16)a.x; pk.h[1] = (_Float16)a.y;
    pk.h[2] = (_Float16)a.z; pk.h[3] = (_Float16)a.w;
    pk.h[4] = (_Float16)b.x; pk.h[5] = (_Float16)b.y;
    pk.h[6] = (_Float16)b.z; pk.h[7] = (_Float16)b.w;
    *(uint4*)(dst + off) = pk.u;
  }
}

// ---------------- k2sum[b,n] = dot(ne[b,n,:], colsum) ----------------------
__global__ __launch_bounds__(256) void k2sum_kernel(const float* __restrict__ ne,
                                                    const float* __restrict__ colsum,
                                                    float* __restrict__ k2sum) {
  const int wave = threadIdx.x >> 6, lane = threadIdx.x & 63;
  const int row = blockIdx.x * 4 + wave;
  float s = 0.f;
#pragma unroll
  for (int i = 0; i < 8; ++i) {
    int k = i * 64 + lane;
    s += ne[(size_t)row * 512 + k] * colsum[k];
  }
#pragma unroll
  for (int off = 32; off; off >>= 1) s += __shfl_down(s, off, 64);
  if (lane == 0) k2sum[row] = s;
}

// ---------------- Q1 = [ge | sc] @ [Wqf | Wqs].T  (K=1026) -----------------
__global__ __launch_bounds__(256) void q1_mfma_kernel(
    const float* __restrict__ ge, const float* __restrict__ sc,
    const float* __restrict__ Wqf, const float* __restrict__ Wqs,
    float* __restrict__ Q1) {
  const int mb = blockIdx.x, nb = blockIdx.y, ks = blockIdx.z;
  const int tid = threadIdx.x;
  const int lane = tid & 63, wave = tid >> 6;
  const int wm = (wave >> 1) * 32, wn = (wave & 1) * 32;

  __shared__ __align__(16) _Float16 As[64][40];
  __shared__ __align__(16) _Float16 Ws[64][40];

  f32x4 acc[2][2] = {};
  const int qd = (lane >> 4) * 8, rr = lane & 15;

  for (int kt = 0; kt < 9; ++kt) {
    const int kb = ks * 288 + kt * 32;
#pragma unroll
    for (int f0 = 0; f0 < 2; ++f0) {
      int f = tid + f0 * 256;
      int r = f >> 3, c4 = (f & 7) * 4;
      int m = mb * 64 + r;
      int e = nb * 64 + r;
#pragma unroll
      for (int j = 0; j < 4; ++j) {
        int k = kb + c4 + j;
        float a = 0.f, w = 0.f;
        if (k < 512) {
          a = ge[(m >> 3) * 512 + k];
          w = Wqf[(size_t)e * 512 + k];
        } else if (k < 1026) {
          a = sc[(size_t)m * 514 + (k - 512)];
          w = Wqs[(size_t)e * 514 + (k - 512)];
        }
        As[r][c4 + j] = (_Float16)a;
        Ws[r][c4 + j] = (_Float16)w;
      }
    }
    __syncthreads();
    f16x8 af[2], bfr[2];
#pragma unroll
    for (int mi = 0; mi < 2; ++mi) af[mi] = *(const f16x8*)&As[wm + mi * 16 + rr][qd];
#pragma unroll
    for (int ni = 0; ni < 2; ++ni) bfr[ni] = *(const f16x8*)&Ws[wn + ni * 16 + rr][qd];
#pragma unroll
    for (int mi = 0; mi < 2; ++mi)
#pragma unroll
      for (int ni = 0; ni < 2; ++ni)
        acc[mi][ni] =
            __builtin_amdgcn_mfma_f32_16x16x32_f16(af[mi], bfr[ni], acc[mi][ni], 0, 0, 0);
    __syncthreads();
  }

  const int col = lane & 15, rq = (lane >> 4) * 4;
#pragma unroll
  for (int mi = 0; mi < 2; ++mi)
#pragma unroll
    for (int ni = 0; ni < 2; ++ni)
#pragma unroll
      for (int r = 0; r < 4; ++r) {
        int m = mb * 64 + wm + mi * 16 + rq + r;
        int e = nb * 64 + wn + ni * 16 + col;
        atomicAdd(&Q1[(size_t)m * 512 + e], acc[mi][ni][r]);
      }
}

// ---------------- fused K1+V GEMM; writes K1 and V-transposed --------------
// R3 grid mapping (nb fastest — proven). A staged as RAW fp32 via
// global_load_lds (zero staging VALU); fp32->f16 cvt at fragment read.
// LDS 64 KB -> 2 blocks/CU.
__global__ __launch_bounds__(256, 2) void gemm_kv(
    const float* __restrict__ A, const _Float16* __restrict__ W1,
    const _Float16* __restrict__ W2, _Float16* __restrict__ K1,
    _Float16* __restrict__ Vt) {
  const int nb = blockIdx.x;  // 0..3
  const int mb = blockIdx.y;  // 0..255
  const int tid = threadIdx.x, lane = tid & 63, wave = tid >> 6;
  const int wm = (wave >> 1) * 64, wn = (wave & 1) * 64;
  const int row0 = mb * 128, col0 = nb * 128;
  const int b = mb >> 2;

  __shared__ __align__(16) float Afs[128 * 64];         // 32 KB fp32, swizzled
  __shared__ __align__(16) _Float16 Wbuf[2][128 * 64];  // 32 KB; epilogue Vts

  f32x4 acc1[4][4] = {}, acc2[4][4] = {};
  const int q = lane >> 4, rr = lane & 15;
  const int wlr = lane >> 3, wlc = lane & 7;
  const int cswz = wlc ^ wlr;  // W chunk swizzle (8 chunks of 8 f16 per row)

  for (int kt = 0; kt < 8; ++kt) {
    const int kbase = kt * 64;
    // W tiles: 128 rows x 8 chunks (16B) each
#pragma unroll
    for (int j = 0; j < 4; ++j) {
      int r = wave * 32 + j * 8 + wlr;
      int ldsrow = (wave * 32 + j * 8) * 64;
      size_t goff = (size_t)(col0 + r) * 512 + kbase + cswz * 8;
      async16(W1 + goff, &Wbuf[0][ldsrow]);
      async16(W2 + goff, &Wbuf[1][ldsrow]);
    }
    // A tile fp32: 128 rows x 16 chunks (16B = 4 floats) each, XOR-swizzled
#pragma unroll
    for (int j = 0; j < 8; ++j) {
      int r = wave * 32 + j * 4 + (lane >> 4);
      int cg = (lane & 15) ^ (r & 7);
      async16(A + (size_t)(row0 + r) * 512 + kbase + cg * 4,
              &Afs[(wave * 32 + j * 4) * 64]);
    }
    __syncthreads();
#pragma unroll
    for (int k0 = 0; k0 < 64; k0 += 32) {
      const int cb = (k0 >> 3) + q;      // f16 chunk (W)
      const int ca = (k0 >> 2) + q * 2;  // fp32 chunk pair base (A)
      f16x8 af[4], b1[4], b2[4];
#pragma unroll
      for (int mi = 0; mi < 4; ++mi) {
        int ra = wm + mi * 16 + rr;
        const float* base = &Afs[ra * 64];
        float4 lo = *(const float4*)(base + (ca ^ (ra & 7)) * 4);
        float4 hi = *(const float4*)(base + ((ca + 1) ^ (ra & 7)) * 4);
        f16x8 v;
        v[0] = (_Float16)lo.x; v[1] = (_Float16)lo.y;
        v[2] = (_Float16)lo.z; v[3] = (_Float16)lo.w;
        v[4] = (_Float16)hi.x; v[5] = (_Float16)hi.y;
        v[6] = (_Float16)hi.z; v[7] = (_Float16)hi.w;
        af[mi] = v;
      }
#pragma unroll
      for (int ni = 0; ni < 4; ++ni) {
        int rw = wn + ni * 16 + rr;
        int slot = cb ^ (rw & 7);
        b1[ni] = *(const f16x8*)&Wbuf[0][rw * 64 + slot * 8];
        b2[ni] = *(const f16x8*)&Wbuf[1][rw * 64 + slot * 8];
      }
#pragma unroll
      for (int mi = 0; mi < 4; ++mi)
#pragma unroll
        for (int ni = 0; ni < 4; ++ni) {
          acc1[mi][ni] =
              __builtin_amdgcn_mfma_f32_16x16x32_f16(af[mi], b1[ni], acc1[mi][ni], 0, 0, 0);
          acc2[mi][ni] =
              __builtin_amdgcn_mfma_f32_16x16x32_f16(af[mi], b2[ni], acc2[mi][ni], 0, 0, 0);
        }
    }
    __syncthreads();
  }

  const int col = lane & 15, rq = (lane >> 4) * 4;
  // K1: natural [n][e] layout
#pragma unroll
  for (int mi = 0; mi < 4; ++mi)
#pragma unroll
    for (int ni = 0; ni < 4; ++ni)
#pragma unroll
      for (int r = 0; r < 4; ++r) {
        size_t m = row0 + wm + mi * 16 + rq + r;
        size_t e = col0 + wn + ni * 16 + col;
        K1[m * 512 + e] = (_Float16)acc1[mi][ni][r];
      }

  // V transposed: frags -> swizzled LDS tile (reuse Afs, 32 KB) -> 256B stores
  _Float16* Vts = (_Float16*)&Afs[0];  // 128 e-rows x 128 n
#pragma unroll
  for (int mi = 0; mi < 4; ++mi)
#pragma unroll
    for (int ni = 0; ni < 4; ++ni) {
      int n0 = wm + mi * 16 + rq;
      int el = wn + ni * 16 + col;
      int cn = n0 >> 3, half = (n0 >> 2) & 1;
      int slot = cn ^ (el & 7);
      union { _Float16 h[4]; unsigned long long u; } pk;
#pragma unroll
      for (int r = 0; r < 4; ++r) pk.h[r] = (_Float16)acc2[mi][ni][r];
      *(unsigned long long*)&Vts[el * 128 + slot * 8 + half * 4] = pk.u;
    }
  __syncthreads();
  const int nbase = row0 & 511;
#pragma unroll
  for (int i = 0; i < 8; ++i) {
    int f = tid + i * 256;
    int el = f >> 4, c16 = f & 15;
    int slot = c16 ^ (el & 7);
    uint4 val = *(const uint4*)&Vts[el * 128 + slot * 8];
    *(uint4*)(Vt + (size_t)b * 262144 + (size_t)(col0 + el) * 512 + nbase + c16 * 8) = val;
  }
}

// ---------------- attention: one block per (b,h), all-MFMA -----------------
__global__ __launch_bounds__(256) void attn_kernel(
    const float* __restrict__ Q1, const _Float16* __restrict__ K1,
    const _Float16* __restrict__ Vt, const int* __restrict__ mask,
    float* __restrict__ heads) {
  const int bid = blockIdx.x;  // 512
  const int b = bid >> 3, h = bid & 7;
  const int tid = threadIdx.x, wave = tid >> 6, lane = tid & 63;
  const int q = lane >> 4, cl = lane & 15;

  __shared__ __align__(16) _Float16 kt[256 * 64];  // 32KB: K-half or Vt-half
  __shared__ __align__(16) _Float16 P[16][520];    // unnormalized probs, f16
  __shared__ float red[4][8];

  f16x8 af[2];
  {
    const float* qp = Q1 + (size_t)(b * 8 + (cl & 7)) * 512 + h * 64 + q * 8;
#pragma unroll
    for (int s = 0; s < 2; ++s) {
      float4 l0 = *(const float4*)(qp + s * 32);
      float4 l1 = *(const float4*)(qp + s * 32 + 4);
      af[s][0] = (_Float16)l0.x; af[s][1] = (_Float16)l0.y;
      af[s][2] = (_Float16)l0.z; af[s][3] = (_Float16)l0.w;
      af[s][4] = (_Float16)l1.x; af[s][5] = (_Float16)l1.y;
      af[s][6] = (_Float16)l1.z; af[s][7] = (_Float16)l1.w;
    }
  }

  // ---- QK^T ----
  f32x4 acc[8] = {};
  const _Float16* Kb = K1 + (size_t)b * 262144 + h * 64;
  for (int h2 = 0; h2 < 2; ++h2) {
#pragma unroll
    for (int j = 0; j < 8; ++j) {
      int r = wave * 64 + j * 8 + (lane >> 3);
      int cg = (lane & 7) ^ (r & 7);
      async16(Kb + (size_t)(h2 * 256 + r) * 512 + cg * 8, &kt[(wave * 64 + j * 8) * 64]);
    }
    __syncthreads();
#pragma unroll
    for (int tt = 0; tt < 4; ++tt) {
      int rn = wave * 64 + tt * 16 + cl;
#pragma unroll
      for (int s = 0; s < 2; ++s) {
        int slot = (s * 4 + q) ^ (cl & 7);
        f16x8 bf = *(const f16x8*)&kt[rn * 64 + slot * 8];
        acc[h2 * 4 + tt] =
            __builtin_amdgcn_mfma_f32_16x16x32_f16(af[s], bf, acc[h2 * 4 + tt], 0, 0, 0);
      }
    }
    __syncthreads();
  }

  // ---- softmax (rows c = q*4+r, valid q<2) ----
  float gmax[4], rsum[4];
  if (q < 2) {
    float mx[4] = {-3e38f, -3e38f, -3e38f, -3e38f};
#pragma unroll
    for (int t = 0; t < 8; ++t) {
      int n = (t >> 2) * 256 + wave * 64 + (t & 3) * 16 + cl;
#pragma unroll
      for (int r = 0; r < 4; ++r) {
        int c = q * 4 + r;
        float x = mask[(size_t)(b * 8 + c) * 512 + n] ? -1e9f : acc[t][r] * 0.125f;
        acc[t][r] = x;
        mx[r] = fmaxf(mx[r], x);
      }
    }
#pragma unroll
    for (int off = 1; off < 16; off <<= 1)
#pragma unroll
      for (int r = 0; r < 4; ++r) mx[r] = fmaxf(mx[r], __shfl_xor(mx[r], off, 64));
    if (cl == 0)
#pragma unroll
      for (int r = 0; r < 4; ++r) red[wave][q * 4 + r] = mx[r];
  }
  __syncthreads();
  if (q < 2) {
#pragma unroll
    for (int r = 0; r < 4; ++r) {
      int c = q * 4 + r;
      gmax[r] = fmaxf(fmaxf(red[0][c], red[1][c]), fmaxf(red[2][c], red[3][c]));
    }
  }
  __syncthreads();
  if (q < 2) {
#pragma unroll
    for (int r = 0; r < 4; ++r) rsum[r] = 0.f;
#pragma unroll
    for (int t = 0; t < 8; ++t) {
      int n = (t >> 2) * 256 + wave * 64 + (t & 3) * 16 + cl;
#pragma unroll
      for (int r = 0; r < 4; ++r) {
        float e = __expf(acc[t][r] - gmax[r]);
        rsum[r] += e;
        P[q * 4 + r][n] = (_Float16)e;
      }
    }
#pragma unroll
    for (int off = 1; off < 16; off <<= 1)
#pragma unroll
      for (int r = 0; r < 4; ++r) rsum[r] += __shfl_xor(rsum[r], off, 64);
    if (cl == 0)
#pragma unroll
      for (int r = 0; r < 4; ++r) red[wave][q * 4 + r] = rsum[r];
  }
  __syncthreads();

  // ---- PV ----
  f32x4 pacc = {};
  const _Float16* Vb = Vt + (size_t)b * 262144 + (size_t)h * 64 * 512;
  for (int h2 = 0; h2 < 2; ++h2) {
#pragma unroll
    for (int j = 0; j < 8; ++j) {
      int r = wave * 16 + j * 2 + (lane >> 5);
      int cg = (lane & 31) ^ (r & 7);
      async16(Vb + (size_t)r * 512 + h2 * 256 + cg * 8, &kt[(wave * 16 + j * 2) * 256]);
    }
    __syncthreads();
    int rn = wave * 16 + cl;
#pragma unroll
    for (int sl = 0; sl < 8; ++sl) {
      int slot = (sl * 4 + q) ^ (cl & 7);
      f16x8 bf = *(const f16x8*)&kt[rn * 256 + slot * 8];
      f16x8 pa = *(const f16x8*)&P[cl][h2 * 256 + sl * 32 + q * 8];
      pacc = __builtin_amdgcn_mfma_f32_16x16x32_f16(pa, bf, pacc, 0, 0, 0);
    }
    __syncthreads();
  }

  if (q < 2) {
#pragma unroll
    for (int r = 0; r < 4; ++r) {
      int c = q * 4 + r;
      float inv = 1.f / (red[0][c] + red[1][c] + red[2][c] + red[3][c]);
      heads[(size_t)(b * 8 + c) * 512 + h * 64 + wave * 16 + cl] = pacc[r] * inv;
    }
  }
}

// ---------------- Q3 = heads @ Wout.T, 64x64 tiles, K-split 2 --------------
__global__ __launch_bounds__(256) void gemm_out64(const float* __restrict__ A,
                                                  const float* __restrict__ W,
                                                  float* __restrict__ C) {
  const int mb = blockIdx.x, nb = blockIdx.y, ks = blockIdx.z;
  const int tid = threadIdx.x;
  const int lane = tid & 63, wave = tid >> 6;
  const int wm = (wave >> 1) * 32, wn = (wave & 1) * 32;

  __shared__ __align__(16) _Float16 As[64][40];
  __shared__ __align__(16) _Float16 Ws[64][40];

  f32x4 acc[2][2] = {};
  const int qd = (lane >> 4) * 8, rr = lane & 15;

  for (int kt = 0; kt < 8; ++kt) {
    const int kb = ks * 256 + kt * 32;
#pragma unroll
    for (int f0 = 0; f0 < 2; ++f0) {
      int f = tid + f0 * 256;
      int r = f >> 3, c4 = (f & 7) * 4;
      float4 a = *(const float4*)(A + (size_t)(mb * 64 + r) * 512 + kb + c4);
      float4 w = *(const float4*)(W + (size_t)(nb * 64 + r) * 512 + kb + c4);
      As[r][c4 + 0] = (_Float16)a.x; As[r][c4 + 1] = (_Float16)a.y;
      As[r][c4 + 2] = (_Float16)a.z; As[r][c4 + 3] = (_Float16)a.w;
      Ws[r][c4 + 0] = (_Float16)w.x; Ws[r][c4 + 1] = (_Float16)w.y;
      Ws[r][c4 + 2] = (_Float16)w.z; Ws[r][c4 + 3] = (_Float16)w.w;
    }
    __syncthreads();
    f16x8 af[2], bfr[2];
#pragma unroll
    for (int mi = 0; mi < 2; ++mi) af[mi] = *(const f16x8*)&As[wm + mi * 16 + rr][qd];
#pragma unroll
    for (int ni = 0; ni < 2; ++ni) bfr[ni] = *(const f16x8*)&Ws[wn + ni * 16 + rr][qd];
#pragma unroll
    for (int mi = 0; mi < 2; ++mi)
#pragma unroll
      for (int ni = 0; ni < 2; ++ni)
        acc[mi][ni] =
            __builtin_amdgcn_mfma_f32_16x16x32_f16(af[mi], bfr[ni], acc[mi][ni], 0, 0, 0);
    __syncthreads();
  }

  const int col = lane & 15, rq = (lane >> 4) * 4;
#pragma unroll
  for (int mi = 0; mi < 2; ++mi)
#pragma unroll
    for (int ni = 0; ni < 2; ++ni)
#pragma unroll
      for (int r = 0; r < 4; ++r) {
        int m = mb * 64 + wm + mi * 16 + rq + r;
        int e = nb * 64 + wn + ni * 16 + col;
        atomicAdd(&C[(size_t)m * 512 + e], acc[mi][ni][r]);
      }
}

// ---------------- fused u_scalar + logits ----------------------------------
__global__ __launch_bounds__(256) void logits_u_kernel(
    const float* __restrict__ Q1, const float* __restrict__ v,
    const float* __restrict__ k2s, const int* __restrict__ mask,
    float* __restrict__ out) {
  const int bc = blockIdx.x;
  const int b = bc >> 3;
  const int tid = threadIdx.x;
  const int wave = tid >> 6, lane = tid & 63;

  float p = tanhf(Q1[(size_t)bc * 512 + tid]) * v[tid] +
            tanhf(Q1[(size_t)bc * 512 + tid + 256]) * v[tid + 256];
#pragma unroll
  for (int off = 32; off; off >>= 1) p += __shfl_down(p, off, 64);
  __shared__ float red[4];
  __shared__ float su;
  if (lane == 0) red[wave] = p;
  __syncthreads();
  if (tid == 0) su = red[0] + red[1] + red[2] + red[3];
  __syncthreads();
  const float u = su;

#pragma unroll
  for (int i = 0; i < 2; ++i) {
    int n = tid + i * 256;
    int idx = bc * 512 + n;
    out[idx] = mask[idx] ? -1e9f
                         : 10.f * tanhf(u * k2s[b * 512 + n] * 0.04419417382415922f);
  }
}

extern "C" void kernel_launch(void* const* d_in, const int* in_sizes, int n_in,
                              void* d_out, int out_size, void* d_ws, size_t ws_size,
                              hipStream_t stream) {
  const float* ne = (const float*)d_in[0];
  const float* ge = (const float*)d_in[1];
  const float* sc = (const float*)d_in[2];
  const int* mask = (const int*)d_in[3];
  const float* Wk1 = (const float*)d_in[4];
  const float* Wv = (const float*)d_in[5];
  const float* Wk2 = (const float*)d_in[6];
  const float* Wqf = (const float*)d_in[7];
  const float* Wout = (const float*)d_in[8];
  const float* Wqs = (const float*)d_in[9];
  const float* v = (const float*)d_in[10];

  float* logits = (float*)d_out;
  float* q3 = (float*)d_out + 262144;

  // ws layout identical to the R4-proven 70.4 MB envelope.
  char* ws = (char*)d_ws;
  _Float16* K1 = (_Float16*)(ws + 0);          // 33,554,432 B  [b][n][e]
  _Float16* Vt = (_Float16*)(ws + 33554432);   // 33,554,432 B  [b][e][n]
  float* Q1 = (float*)(ws + 67108864);         // 1,048,576 B
  float* heads = (float*)(ws + 68157440);      // 1,048,576 B
  float* k2sum = (float*)(ws + 69206016);      // 131,072 B
  float* colsum = (float*)(ws + 69337088);     // 2,048 B
  _Float16* W1h = (_Float16*)(ws + 69339136);  // 524,288 B
  _Float16* W2h = (_Float16*)(ws + 69863424);  // 524,288 B

  hipMemsetAsync(Q1, 0, 1048576, stream);
  hipMemsetAsync(q3, 0, 1048576, stream);
  prep_w<<<272, 256, 0, stream>>>(Wk1, Wv, Wk2, W1h, W2h, colsum);
  k2sum_kernel<<<8192, 256, 0, stream>>>(ne, colsum, k2sum);
  q1_mfma_kernel<<<dim3(8, 8, 4), 256, 0, stream>>>(ge, sc, Wqf, Wqs, Q1);
  gemm_kv<<<dim3(4, 256), 256, 0, stream>>>(ne, W1h, W2h, K1, Vt);
  attn_kernel<<<512, 256, 0, stream>>>(Q1, K1, Vt, mask, heads);
  gemm_out64<<<dim3(8, 8, 2), 256, 0, stream>>>(heads, Wout, q3);
  logits_u_kernel<<<512, 256, 0, stream>>>(Q1, v, k2sum, mask, logits);
}

// Round 10
// 222.561 us; speedup vs baseline: 1.2202x; 1.0133x over previous
//
#include <hip/hip_runtime.h>

// Dims fixed by the problem: B=64, C=8, N=512, E=512, H=8, dh=64
// logits out: [B, C*N] = 262144 floats at d_out[0]
// Q3 out:     [B, C, E] = 262144 floats at d_out[262144]

typedef _Float16 f16x8 __attribute__((ext_vector_type(8)));
typedef float f32x4 __attribute__((ext_vector_type(4)));

__device__ __forceinline__ void async16(const void* g, void* l) {
  __builtin_amdgcn_global_load_lds(
      (const __attribute__((address_space(1))) unsigned int*)g,
      (__attribute__((address_space(3))) unsigned int*)l, 16, 0, 0);
}

// ---------------- prep: colsum(Wk2) + convert Wk1/Wv to f16 ----------------
__global__ __launch_bounds__(256) void prep_w(const float* __restrict__ Wk1,
                                              const float* __restrict__ Wv,
                                              const float* __restrict__ Wk2,
                                              _Float16* __restrict__ W1h,
                                              _Float16* __restrict__ W2h,
                                              float* __restrict__ colsum) {
  const int bid = blockIdx.x;
  if (bid < 16) {
    const int tx = threadIdx.x & 31, ty = threadIdx.x >> 5;
    const int col = bid * 32 + tx;
    float s = 0.f;
#pragma unroll 4
    for (int e = ty * 64; e < ty * 64 + 64; ++e) s += Wk2[e * 512 + col];
    __shared__ float red[8][32];
    red[ty][tx] = s;
    __syncthreads();
    if (ty == 0) {
      float t = 0.f;
#pragma unroll
      for (int g = 0; g < 8; ++g) t += red[g][tx];
      colsum[col] = t;
    }
  } else {
    const int cb = bid - 16;
    const float* src = (cb < 128) ? Wk1 : Wv;
    _Float16* dst = (cb < 128) ? W1h : W2h;
    const size_t off = (size_t)(cb & 127) * 2048 + threadIdx.x * 8;
    float4 a = *(const float4*)(src + off);
    float4 b = *(const float4*)(src + off + 4);
    union { _Float16 h[8]; uint4 u; } pk;
    pk.h[0] = (_Float16)a.x; pk.h[1] = (_Float16)a.y;
    pk.h[2] = (_Float16)a.z; pk.h[3] = (_Float16)a.w;
    pk.h[4] = (_Float16)b.x; pk.h[5] = (_Float16)b.y;
    pk.h[6] = (_Float16)b.z; pk.h[7] = (_Float16)b.w;
    *(uint4*)(dst + off) = pk.u;
  }
}

// ---------------- Q1 = [ge | sc] @ [Wqf | Wqs].T  (K=1026) -----------------
__global__ __launch_bounds__(256) void q1_mfma_kernel(
    const float* __restrict__ ge, const float* __restrict__ sc,
    const float* __restrict__ Wqf, const float* __restrict__ Wqs,
    float* __restrict__ Q1) {
  const int mb = blockIdx.x, nb = blockIdx.y, ks = blockIdx.z;
  const int tid = threadIdx.x;
  const int lane = tid & 63, wave = tid >> 6;
  const int wm = (wave >> 1) * 32, wn = (wave & 1) * 32;

  __shared__ __align__(16) _Float16 As[64][40];
  __shared__ __align__(16) _Float16 Ws[64][40];

  f32x4 acc[2][2] = {};
  const int qd = (lane >> 4) * 8, rr = lane & 15;

  for (int kt = 0; kt < 9; ++kt) {
    const int kb = ks * 288 + kt * 32;
#pragma unroll
    for (int f0 = 0; f0 < 2; ++f0) {
      int f = tid + f0 * 256;
      int r = f >> 3, c4 = (f & 7) * 4;
      int m = mb * 64 + r;
      int e = nb * 64 + r;
#pragma unroll
      for (int j = 0; j < 4; ++j) {
        int k = kb + c4 + j;
        float a = 0.f, w = 0.f;
        if (k < 512) {
          a = ge[(m >> 3) * 512 + k];
          w = Wqf[(size_t)e * 512 + k];
        } else if (k < 1026) {
          a = sc[(size_t)m * 514 + (k - 512)];
          w = Wqs[(size_t)e * 514 + (k - 512)];
        }
        As[r][c4 + j] = (_Float16)a;
        Ws[r][c4 + j] = (_Float16)w;
      }
    }
    __syncthreads();
    f16x8 af[2], bfr[2];
#pragma unroll
    for (int mi = 0; mi < 2; ++mi) af[mi] = *(const f16x8*)&As[wm + mi * 16 + rr][qd];
#pragma unroll
    for (int ni = 0; ni < 2; ++ni) bfr[ni] = *(const f16x8*)&Ws[wn + ni * 16 + rr][qd];
#pragma unroll
    for (int mi = 0; mi < 2; ++mi)
#pragma unroll
      for (int ni = 0; ni < 2; ++ni)
        acc[mi][ni] =
            __builtin_amdgcn_mfma_f32_16x16x32_f16(af[mi], bfr[ni], acc[mi][ni], 0, 0, 0);
    __syncthreads();
  }

  const int col = lane & 15, rq = (lane >> 4) * 4;
#pragma unroll
  for (int mi = 0; mi < 2; ++mi)
#pragma unroll
    for (int ni = 0; ni < 2; ++ni)
#pragma unroll
      for (int r = 0; r < 4; ++r) {
        int m = mb * 64 + wm + mi * 16 + rq + r;
        int e = nb * 64 + wn + ni * 16 + col;
        atomicAdd(&Q1[(size_t)m * 512 + e], acc[mi][ni][r]);
      }
}

// ---------------- fused K1+V GEMM + k2sum; K1 and V-transposed -------------
// Exact R7 structure (BK=64, launch_bounds(256,2), 64 KB LDS — proven PASS;
// the kernel is VGPR-bound to 8 waves/CU, 4-blocks/CU bound is infeasible
// with 128 accumulator VGPRs). nb==0 blocks fuse k2sum by re-reading the
// staged fp32 A tile (2 threads/row, no atomics).
__global__ __launch_bounds__(256, 2) void gemm_kv(
    const float* __restrict__ A, const _Float16* __restrict__ W1,
    const _Float16* __restrict__ W2, const float* __restrict__ colsum,
    _Float16* __restrict__ K1, _Float16* __restrict__ Vt,
    float* __restrict__ k2sum) {
  const int nb = blockIdx.x;  // 0..3 fastest (R4 proved same-XCD grouping hurts)
  const int mb = blockIdx.y;  // 0..255
  const int tid = threadIdx.x, lane = tid & 63, wave = tid >> 6;
  const int wm = (wave >> 1) * 64, wn = (wave & 1) * 64;
  const int row0 = mb * 128, col0 = nb * 128;
  const int b = mb >> 2;

  __shared__ __align__(16) float Afs[128 * 64];         // 32 KB fp32, swizzled
  __shared__ __align__(16) _Float16 Wbuf[2][128 * 64];  // 32 KB; epilogue Vts

  f32x4 acc1[4][4] = {}, acc2[4][4] = {};
  float k2p = 0.f;
  const int q = lane >> 4, rr = lane & 15;
  const int wlr = lane >> 3, wlc = lane & 7;
  const int cswz = wlc ^ wlr;  // W chunk swizzle (8 chunks of 8 f16 per row)

  for (int kt = 0; kt < 8; ++kt) {
    const int kbase = kt * 64;
    // W tiles: 128 rows x 8 chunks (16B) each
#pragma unroll
    for (int j = 0; j < 4; ++j) {
      int r = wave * 32 + j * 8 + wlr;
      int ldsrow = (wave * 32 + j * 8) * 64;
      size_t goff = (size_t)(col0 + r) * 512 + kbase + cswz * 8;
      async16(W1 + goff, &Wbuf[0][ldsrow]);
      async16(W2 + goff, &Wbuf[1][ldsrow]);
    }
    // A tile fp32: 128 rows x 16 chunks (16B = 4 floats) each, XOR-swizzled
#pragma unroll
    for (int j = 0; j < 8; ++j) {
      int r = wave * 32 + j * 4 + (lane >> 4);
      int cg = (lane & 15) ^ (r & 7);
      async16(A + (size_t)(row0 + r) * 512 + kbase + cg * 4,
              &Afs[(wave * 32 + j * 4) * 64]);
    }
    __syncthreads();
#pragma unroll
    for (int k0 = 0; k0 < 64; k0 += 32) {
      const int cb = (k0 >> 3) + q;      // f16 chunk (W)
      const int ca = (k0 >> 2) + q * 2;  // fp32 chunk pair base (A)
      f16x8 af[4], b1[4], b2[4];
#pragma unroll
      for (int mi = 0; mi < 4; ++mi) {
        int ra = wm + mi * 16 + rr;
        const float* base = &Afs[ra * 64];
        float4 lo = *(const float4*)(base + ((ca ^ (ra & 7)) * 4));
        float4 hi = *(const float4*)(base + (((ca + 1) ^ (ra & 7)) * 4));
        f16x8 v;
        v[0] = (_Float16)lo.x; v[1] = (_Float16)lo.y;
        v[2] = (_Float16)lo.z; v[3] = (_Float16)lo.w;
        v[4] = (_Float16)hi.x; v[5] = (_Float16)hi.y;
        v[6] = (_Float16)hi.z; v[7] = (_Float16)hi.w;
        af[mi] = v;
      }
#pragma unroll
      for (int ni = 0; ni < 4; ++ni) {
        int rw = wn + ni * 16 + rr;
        int slot = cb ^ (rw & 7);
        b1[ni] = *(const f16x8*)&Wbuf[0][rw * 64 + slot * 8];
        b2[ni] = *(const f16x8*)&Wbuf[1][rw * 64 + slot * 8];
      }
#pragma unroll
      for (int mi = 0; mi < 4; ++mi)
#pragma unroll
        for (int ni = 0; ni < 4; ++ni) {
          acc1[mi][ni] =
              __builtin_amdgcn_mfma_f32_16x16x32_f16(af[mi], b1[ni], acc1[mi][ni], 0, 0, 0);
          acc2[mi][ni] =
              __builtin_amdgcn_mfma_f32_16x16x32_f16(af[mi], b2[ni], acc2[mi][ni], 0, 0, 0);
        }
    }
    // fused k2sum: nb==0 blocks dot the staged fp32 A tile with colsum.
    // thread t owns row (t>>1), chunks (t&1)*8 .. +7 (data valid until the
    // trailing barrier).
    if (nb == 0) {
      int r = tid >> 1, cb0 = (tid & 1) * 8;
      const float* csp = colsum + kbase;
#pragma unroll
      for (int c = cb0; c < cb0 + 8; ++c) {
        int slot = c ^ (r & 7);
        float4 av = *(const float4*)&Afs[r * 64 + slot * 4];
        float4 cv = *(const float4*)(csp + c * 4);
        k2p += av.x * cv.x + av.y * cv.y + av.z * cv.z + av.w * cv.w;
      }
    }
    __syncthreads();
  }

  if (nb == 0) {
    k2p += __shfl_xor(k2p, 1, 64);
    if ((tid & 1) == 0) k2sum[row0 + (tid >> 1)] = k2p;
  }

  const int col = lane & 15, rq = (lane >> 4) * 4;
  // K1: natural [n][e] layout
#pragma unroll
  for (int mi = 0; mi < 4; ++mi)
#pragma unroll
    for (int ni = 0; ni < 4; ++ni)
#pragma unroll
      for (int r = 0; r < 4; ++r) {
        size_t m = row0 + wm + mi * 16 + rq + r;
        size_t e = col0 + wn + ni * 16 + col;
        K1[m * 512 + e] = (_Float16)acc1[mi][ni][r];
      }

  // V transposed: frags -> swizzled LDS tile (reuse Afs, 32 KB) -> 256B stores
  _Float16* Vts = (_Float16*)&Afs[0];  // 128 e-rows x 128 n
#pragma unroll
  for (int mi = 0; mi < 4; ++mi)
#pragma unroll
    for (int ni = 0; ni < 4; ++ni) {
      int n0 = wm + mi * 16 + rq;
      int el = wn + ni * 16 + col;
      int cn = n0 >> 3, half = (n0 >> 2) & 1;
      int slot = cn ^ (el & 7);
      union { _Float16 h[4]; unsigned long long u; } pk;
#pragma unroll
      for (int r = 0; r < 4; ++r) pk.h[r] = (_Float16)acc2[mi][ni][r];
      *(unsigned long long*)&Vts[el * 128 + slot * 8 + half * 4] = pk.u;
    }
  __syncthreads();
  const int nbase = row0 & 511;
#pragma unroll
  for (int i = 0; i < 8; ++i) {
    int f = tid + i * 256;
    int el = f >> 4, c16 = f & 15;
    int slot = c16 ^ (el & 7);
    uint4 val = *(const uint4*)&Vts[el * 128 + slot * 8];
    *(uint4*)(Vt + (size_t)b * 262144 + (size_t)(col0 + el) * 512 + nbase + c16 * 8) = val;
  }
}

// ---------------- attention: one block per (b,h), all-MFMA -----------------
// R7 structure + V-half-0 prefetch hidden under softmax (the softmax-ending
// __syncthreads drains vmcnt, so the prefetch is complete before PV).
__global__ __launch_bounds__(256) void attn_kernel(
    const float* __restrict__ Q1, const _Float16* __restrict__ K1,
    const _Float16* __restrict__ Vt, const int* __restrict__ mask,
    float* __restrict__ heads) {
  const int bid = blockIdx.x;  // 512
  const int b = bid >> 3, h = bid & 7;
  const int tid = threadIdx.x, wave = tid >> 6, lane = tid & 63;
  const int q = lane >> 4, cl = lane & 15;

  __shared__ __align__(16) _Float16 kt[256 * 64];  // 32KB: K-half or Vt-half
  __shared__ __align__(16) _Float16 P[16][520];    // unnormalized probs, f16
  __shared__ float red[4][8];

  f16x8 af[2];
  {
    const float* qp = Q1 + (size_t)(b * 8 + (cl & 7)) * 512 + h * 64 + q * 8;
#pragma unroll
    for (int s = 0; s < 2; ++s) {
      float4 l0 = *(const float4*)(qp + s * 32);
      float4 l1 = *(const float4*)(qp + s * 32 + 4);
      af[s][0] = (_Float16)l0.x; af[s][1] = (_Float16)l0.y;
      af[s][2] = (_Float16)l0.z; af[s][3] = (_Float16)l0.w;
      af[s][4] = (_Float16)l1.x; af[s][5] = (_Float16)l1.y;
      af[s][6] = (_Float16)l1.z; af[s][7] = (_Float16)l1.w;
    }
  }

  // ---- QK^T ----
  f32x4 acc[8] = {};
  const _Float16* Kb = K1 + (size_t)b * 262144 + h * 64;
  for (int h2 = 0; h2 < 2; ++h2) {
#pragma unroll
    for (int j = 0; j < 8; ++j) {
      int r = wave * 64 + j * 8 + (lane >> 3);
      int cg = (lane & 7) ^ (r & 7);
      async16(Kb + (size_t)(h2 * 256 + r) * 512 + cg * 8, &kt[(wave * 64 + j * 8) * 64]);
    }
    __syncthreads();
#pragma unroll
    for (int tt = 0; tt < 4; ++tt) {
      int rn = wave * 64 + tt * 16 + cl;
#pragma unroll
      for (int s = 0; s < 2; ++s) {
        int slot = (s * 4 + q) ^ (cl & 7);
        f16x8 bf = *(const f16x8*)&kt[rn * 64 + slot * 8];
        acc[h2 * 4 + tt] =
            __builtin_amdgcn_mfma_f32_16x16x32_f16(af[s], bf, acc[h2 * 4 + tt], 0, 0, 0);
      }
    }
    __syncthreads();
  }

  // ---- prefetch V half 0 into kt (hidden under softmax) ----
  const _Float16* Vb = Vt + (size_t)b * 262144 + (size_t)h * 64 * 512;
#pragma unroll
  for (int j = 0; j < 8; ++j) {
    int r = wave * 16 + j * 2 + (lane >> 5);
    int cg = (lane & 31) ^ (r & 7);
    async16(Vb + (size_t)r * 512 + cg * 8, &kt[(wave * 16 + j * 2) * 256]);
  }

  // ---- softmax (rows c = q*4+r, valid q<2) ----
  float gmax[4], rsum[4];
  if (q < 2) {
    float mx[4] = {-3e38f, -3e38f, -3e38f, -3e38f};
#pragma unroll
    for (int t = 0; t < 8; ++t) {
      int n = (t >> 2) * 256 + wave * 64 + (t & 3) * 16 + cl;
#pragma unroll
      for (int r = 0; r < 4; ++r) {
        int c = q * 4 + r;
        float x = mask[(size_t)(b * 8 + c) * 512 + n] ? -1e9f : acc[t][r] * 0.125f;
        acc[t][r] = x;
        mx[r] = fmaxf(mx[r], x);
      }
    }
#pragma unroll
    for (int off = 1; off < 16; off <<= 1)
#pragma unroll
      for (int r = 0; r < 4; ++r) mx[r] = fmaxf(mx[r], __shfl_xor(mx[r], off, 64));
    if (cl == 0)
#pragma unroll
      for (int r = 0; r < 4; ++r) red[wave][q * 4 + r] = mx[r];
  }
  __syncthreads();
  if (q < 2) {
#pragma unroll
    for (int r = 0; r < 4; ++r) {
      int c = q * 4 + r;
      gmax[r] = fmaxf(fmaxf(red[0][c], red[1][c]), fmaxf(red[2][c], red[3][c]));
    }
  }
  __syncthreads();
  if (q < 2) {
#pragma unroll
    for (int r = 0; r < 4; ++r) rsum[r] = 0.f;
#pragma unroll
    for (int t = 0; t < 8; ++t) {
      int n = (t >> 2) * 256 + wave * 64 + (t & 3) * 16 + cl;
#pragma unroll
      for (int r = 0; r < 4; ++r) {
        float e = __expf(acc[t][r] - gmax[r]);
        rsum[r] += e;
        P[q * 4 + r][n] = (_Float16)e;
      }
    }
#pragma unroll
    for (int off = 1; off < 16; off <<= 1)
#pragma unroll
      for (int r = 0; r < 4; ++r) rsum[r] += __shfl_xor(rsum[r], off, 64);
    if (cl == 0)
#pragma unroll
      for (int r = 0; r < 4; ++r) red[wave][q * 4 + r] = rsum[r];
  }
  __syncthreads();  // also drains the V half-0 prefetch

  // ---- PV ----
  f32x4 pacc = {};
  const int rn = wave * 16 + cl;
  // half 0: already staged
#pragma unroll
  for (int sl = 0; sl < 8; ++sl) {
    int slot = (sl * 4 + q) ^ (cl & 7);
    f16x8 bf = *(const f16x8*)&kt[rn * 256 + slot * 8];
    f16x8 pa = *(const f16x8*)&P[cl][sl * 32 + q * 8];
    pacc = __builtin_amdgcn_mfma_f32_16x16x32_f16(pa, bf, pacc, 0, 0, 0);
  }
  __syncthreads();
  // half 1: stage + consume
#pragma unroll
  for (int j = 0; j < 8; ++j) {
    int r = wave * 16 + j * 2 + (lane >> 5);
    int cg = (lane & 31) ^ (r & 7);
    async16(Vb + (size_t)r * 512 + 256 + cg * 8, &kt[(wave * 16 + j * 2) * 256]);
  }
  __syncthreads();
#pragma unroll
  for (int sl = 0; sl < 8; ++sl) {
    int slot = (sl * 4 + q) ^ (cl & 7);
    f16x8 bf = *(const f16x8*)&kt[rn * 256 + slot * 8];
    f16x8 pa = *(const f16x8*)&P[cl][256 + sl * 32 + q * 8];
    pacc = __builtin_amdgcn_mfma_f32_16x16x32_f16(pa, bf, pacc, 0, 0, 0);
  }

  if (q < 2) {
#pragma unroll
    for (int r = 0; r < 4; ++r) {
      int c = q * 4 + r;
      float inv = 1.f / (red[0][c] + red[1][c] + red[2][c] + red[3][c]);
      heads[(size_t)(b * 8 + c) * 512 + h * 64 + wave * 16 + cl] = pacc[r] * inv;
    }
  }
}

// ---------------- Q3 = heads @ Wout.T, 64x64 tiles, K-split 2 --------------
__global__ __launch_bounds__(256) void gemm_out64(const float* __restrict__ A,
                                                  const float* __restrict__ W,
                                                  float* __restrict__ C) {
  const int mb = blockIdx.x, nb = blockIdx.y, ks = blockIdx.z;
  const int tid = threadIdx.x;
  const int lane = tid & 63, wave = tid >> 6;
  const int wm = (wave >> 1) * 32, wn = (wave & 1) * 32;

  __shared__ __align__(16) _Float16 As[64][40];
  __shared__ __align__(16) _Float16 Ws[64][40];

  f32x4 acc[2][2] = {};
  const int qd = (lane >> 4) * 8, rr = lane & 15;

  for (int kt = 0; kt < 8; ++kt) {
    const int kb = ks * 256 + kt * 32;
#pragma unroll
    for (int f0 = 0; f0 < 2; ++f0) {
      int f = tid + f0 * 256;
      int r = f >> 3, c4 = (f & 7) * 4;
      float4 a = *(const float4*)(A + (size_t)(mb * 64 + r) * 512 + kb + c4);
      float4 w = *(const float4*)(W + (size_t)(nb * 64 + r) * 512 + kb + c4);
      As[r][c4 + 0] = (_Float16)a.x; As[r][c4 + 1] = (_Float16)a.y;
      As[r][c4 + 2] = (_Float16)a.z; As[r][c4 + 3] = (_Float16)a.w;
      Ws[r][c4 + 0] = (_Float16)w.x; Ws[r][c4 + 1] = (_Float16)w.y;
      Ws[r][c4 + 2] = (_Float16)w.z; Ws[r][c4 + 3] = (_Float16)w.w;
    }
    __syncthreads();
    f16x8 af[2], bfr[2];
#pragma unroll
    for (int mi = 0; mi < 2; ++mi) af[mi] = *(const f16x8*)&As[wm + mi * 16 + rr][qd];
#pragma unroll
    for (int ni = 0; ni < 2; ++ni) bfr[ni] = *(const f16x8*)&Ws[wn + ni * 16 + rr][qd];
#pragma unroll
    for (int mi = 0; mi < 2; ++mi)
#pragma unroll
      for (int ni = 0; ni < 2; ++ni)
        acc[mi][ni] =
            __builtin_amdgcn_mfma_f32_16x16x32_f16(af[mi], bfr[ni], acc[mi][ni], 0, 0, 0);
    __syncthreads();
  }

  const int col = lane & 15, rq = (lane >> 4) * 4;
#pragma unroll
  for (int mi = 0; mi < 2; ++mi)
#pragma unroll
    for (int ni = 0; ni < 2; ++ni)
#pragma unroll
      for (int r = 0; r < 4; ++r) {
        int m = mb * 64 + wm + mi * 16 + rq + r;
        int e = nb * 64 + wn + ni * 16 + col;
        atomicAdd(&C[(size_t)m * 512 + e], acc[mi][ni][r]);
      }
}

// ---------------- fused u_scalar + logits ----------------------------------
__global__ __launch_bounds__(256) void logits_u_kernel(
    const float* __restrict__ Q1, const float* __restrict__ v,
    const float* __restrict__ k2s, const int* __restrict__ mask,
    float* __restrict__ out) {
  const int bc = blockIdx.x;
  const int b = bc >> 3;
  const int tid = threadIdx.x;
  const int wave = tid >> 6, lane = tid & 63;

  float p = tanhf(Q1[(size_t)bc * 512 + tid]) * v[tid] +
            tanhf(Q1[(size_t)bc * 512 + tid + 256]) * v[tid + 256];
#pragma unroll
  for (int off = 32; off; off >>= 1) p += __shfl_down(p, off, 64);
  __shared__ float red[4];
  __shared__ float su;
  if (lane == 0) red[wave] = p;
  __syncthreads();
  if (tid == 0) su = red[0] + red[1] + red[2] + red[3];
  __syncthreads();
  const float u = su;

#pragma unroll
  for (int i = 0; i < 2; ++i) {
    int n = tid + i * 256;
    int idx = bc * 512 + n;
    out[idx] = mask[idx] ? -1e9f
                         : 10.f * tanhf(u * k2s[b * 512 + n] * 0.04419417382415922f);
  }
}

extern "C" void kernel_launch(void* const* d_in, const int* in_sizes, int n_in,
                              void* d_out, int out_size, void* d_ws, size_t ws_size,
                              hipStream_t stream) {
  const float* ne = (const float*)d_in[0];
  const float* ge = (const float*)d_in[1];
  const float* sc = (const float*)d_in[2];
  const int* mask = (const int*)d_in[3];
  const float* Wk1 = (const float*)d_in[4];
  const float* Wv = (const float*)d_in[5];
  const float* Wk2 = (const float*)d_in[6];
  const float* Wqf = (const float*)d_in[7];
  const float* Wout = (const float*)d_in[8];
  const float* Wqs = (const float*)d_in[9];
  const float* v = (const float*)d_in[10];

  float* logits = (float*)d_out;
  float* q3 = (float*)d_out + 262144;

  // ws layout: R4/R7-proven 70.4 MB envelope.
  char* ws = (char*)d_ws;
  _Float16* K1 = (_Float16*)(ws + 0);          // 33,554,432 B  [b][n][e]
  _Float16* Vt = (_Float16*)(ws + 33554432);   // 33,554,432 B  [b][e][n]
  float* Q1 = (float*)(ws + 67108864);         // 1,048,576 B
  float* heads = (float*)(ws + 68157440);      // 1,048,576 B
  float* k2sum = (float*)(ws + 69206016);      // 131,072 B
  float* colsum = (float*)(ws + 69337088);     // 2,048 B
  _Float16* W1h = (_Float16*)(ws + 69339136);  // 524,288 B
  _Float16* W2h = (_Float16*)(ws + 69863424);  // 524,288 B

  hipMemsetAsync(Q1, 0, 1048576, stream);
  hipMemsetAsync(q3, 0, 1048576, stream);
  prep_w<<<272, 256, 0, stream>>>(Wk1, Wv, Wk2, W1h, W2h, colsum);
  q1_mfma_kernel<<<dim3(8, 8, 4), 256, 0, stream>>>(ge, sc, Wqf, Wqs, Q1);
  gemm_kv<<<dim3(4, 256), 256, 0, stream>>>(ne, W1h, W2h, colsum, K1, Vt, k2sum);
  attn_kernel<<<512, 256, 0, stream>>>(Q1, K1, Vt, mask, heads);
  gemm_out64<<<dim3(8, 8, 2), 256, 0, stream>>>(heads, Wout, q3);
  logits_u_kernel<<<512, 256, 0, stream>>>(Q1, v, k2sum, mask, logits);
}